// Round 17
// baseline (4771.053 us; speedup 1.0000x reference)
//
#include <hip/hip_runtime.h>
#include <math.h>

typedef _Float16 f16;
typedef f16 f16x2 __attribute__((ext_vector_type(2)));
typedef f16 f16x4 __attribute__((ext_vector_type(4)));
typedef f16 f16x8 __attribute__((ext_vector_type(8)));
typedef float f32x4 __attribute__((ext_vector_type(4)));

#define HDIM 1024
#define SEQ  2048
#define NBLK 16    // recurrence blocks
#define NGWK 240   // persistent gemm worker blocks
#define RPB  64    // rows of W_hh per recurrence block
#define NTIL 4000  // 16 M-strips x 250 N-tiles

// ---------------- clear comm arrays ----------------
__global__ void k_clear(unsigned long long* __restrict__ p, int n,
                        unsigned* __restrict__ sR, int nr,
                        unsigned* __restrict__ sG, int ng) {
  int stride = gridDim.x * blockDim.x;
  int id = blockIdx.x * blockDim.x + threadIdx.x;
  for (int i = id; i < n; i += stride) p[i] = 0ULL;
  for (int i = id; i < nr; i += stride) sR[i] = 0u;
  for (int i = id; i < ng; i += stride) sG[i] = 0u;
}

// ---------------- f32 -> f16 convert (vec4, grid-stride) ----------------
__global__ void k_cvt(const float* __restrict__ in, f16* __restrict__ out, int n4) {
  int stride = gridDim.x * blockDim.x;
  for (int i = blockIdx.x * blockDim.x + threadIdx.x; i < n4; i += stride) {
    float4 v = ((const float4*)in)[i];
    f16x4 o = { (f16)v.x, (f16)v.y, (f16)v.z, (f16)v.w };
    ((f16x4*)out)[i] = o;
  }
}

__global__ void k_bias(const float* __restrict__ a, const float* __restrict__ b,
                       float* __restrict__ o) {
  int i = blockIdx.x * blockDim.x + threadIdx.x;
  if (i < HDIM) o[i] = a[i] + b[i];
}

// ---------------- standalone 256-thr GEMM (xp projection only) ----------------
__global__ __launch_bounds__(256) void k_gemm(
    const f16* __restrict__ A, const f16* __restrict__ B,
    const float* __restrict__ bias, float* __restrict__ C, int N)
{
  const int K = 1024;
  __shared__ __align__(16) f16 lsA[128 * 32];
  __shared__ __align__(16) f16 lsB[128 * 32];
  const int tid = threadIdx.x;
  const int l   = tid & 63;
  const int wv  = tid >> 6;
  const int mb  = blockIdx.y * 128;
  const int nb  = blockIdx.x * 128;
  const int wm  = (wv >> 1) * 64;
  const int wn  = (wv & 1) * 64;

  f32x4 acc[4][4] = {};

  for (int kt = 0; kt < K; kt += 32) {
    uint4 ra[2], rb[2];
#pragma unroll
    for (int i = 0; i < 2; ++i) {
      int c = tid + i * 256;
      int row = c >> 2, off = (c & 3) * 8;
      ra[i] = *(const uint4*)(A + (size_t)(mb + row) * K + kt + off);
      rb[i] = *(const uint4*)(B + (size_t)(nb + row) * K + kt + off);
    }
    __syncthreads();
#pragma unroll
    for (int i = 0; i < 2; ++i) {
      int c = tid + i * 256;
      *(uint4*)(lsA + c * 8) = ra[i];
      *(uint4*)(lsB + c * 8) = rb[i];
    }
    __syncthreads();

    f16x8 af[4], bf[4];
#pragma unroll
    for (int m = 0; m < 4; ++m)
      af[m] = *(const f16x8*)(lsA + (wm + m * 16 + (l & 15)) * 32 + (l >> 4) * 8);
#pragma unroll
    for (int n = 0; n < 4; ++n)
      bf[n] = *(const f16x8*)(lsB + (wn + n * 16 + (l & 15)) * 32 + (l >> 4) * 8);
#pragma unroll
    for (int m = 0; m < 4; ++m)
#pragma unroll
      for (int n = 0; n < 4; ++n)
        acc[m][n] = __builtin_amdgcn_mfma_f32_16x16x32_f16(af[m], bf[n], acc[m][n], 0, 0, 0);
  }

#pragma unroll
  for (int n = 0; n < 4; ++n) {
    int col = nb + wn + n * 16 + (l & 15);
    float bv = bias[col];
#pragma unroll
    for (int m = 0; m < 4; ++m) {
#pragma unroll
      for (int j = 0; j < 4; ++j) {
        int row = mb + wm + m * 16 + (l >> 4) * 4 + j;
        C[(size_t)row * N + col] = acc[m][n][j] + bv;
      }
    }
  }
}

// ---- comm primitives (proven): WRITER = agent-scope atomic RMW (exchange),
// executes AT the MALL, leaves line dirty-resident. READER = agent-scope
// atomic LOAD. Tag-in-data absorbs reorder; staleness only delays. ----
__device__ __forceinline__ void pub64(unsigned long long* p, unsigned long long v) {
  (void)__hip_atomic_exchange(p, v, __ATOMIC_RELAXED, __HIP_MEMORY_SCOPE_AGENT);
}
__device__ __forceinline__ void pub32(unsigned* p, unsigned v) {
  (void)__hip_atomic_exchange(p, v, __ATOMIC_RELAXED, __HIP_MEMORY_SCOPE_AGENT);
}
__device__ __forceinline__ unsigned long long rd64(const unsigned long long* p) {
  return __hip_atomic_load(p, __ATOMIC_RELAXED, __HIP_MEMORY_SCOPE_AGENT);
}
__device__ __forceinline__ unsigned rd32(const unsigned* p) {
  return __hip_atomic_load(p, __ATOMIC_RELAXED, __HIP_MEMORY_SCOPE_AGENT);
}

// ---------------- FUSED: recurrence (blocks 0-15) + head GEMM (16-255) -------
// R17 = R16 + SPECULATIVE CONCURRENT SWEEP: in the gate poll, once the
// previous ballot showed >=12/16 blocks ready (and on the 1st iteration),
// issue the 8 payload loads BEFORE the gate read. They stay in flight while
// gate+ballot resolve (waitcnt lands at first use of u[], after the ballot);
// on gate pass the payload is already arriving -> validate tags, skip the
// serialized sweep RT. Residual validated sweep kept for rare misses.
// Everything else identical to R16 (double-buffered hl, no barrier B,
// per-strip sumG behind strip-boundary barrier).
__global__ __launch_bounds__(1024, 4) void k_main(
    const float* __restrict__ W,              // W_hh f32 [H][H]
    const float* __restrict__ xp,             // [SEQ][H] f32
    unsigned long long* __restrict__ pairs,   // [2][512] ring: tag<<32|f16x2
    unsigned* __restrict__ sumR,              // [16*32] persistent gate tags
    unsigned* __restrict__ sumG,              // [16 strips][16 blocks]
    f16* __restrict__ hs,                     // [(SEQ+1)][H] clean copy
    const f16* __restrict__ Wfc,              // [32000][1024] f16
    const float* __restrict__ bfc,            // [32000]
    float* __restrict__ out)                  // [2048][32000]
{
  __shared__ unsigned hl[2 * 544]; // DOUBLE-BUFFERED bounce (17-stride swizzle)
  __shared__ int s_dead;
  __shared__ __align__(16) f16 lsA[128 * 32];  // gemm tiles
  __shared__ __align__(16) f16 lsB[128 * 32];

  const int tid = threadIdx.x;
  const int l   = tid & 63;
  const int wv  = tid >> 6;

  if (blockIdx.x < NBLK) {
    // ================= recurrence =================
    const int b   = blockIdx.x;
    const int w   = wv;
    const int hfl = l >> 5;
    const int ch  = l & 31;
    const int r0  = b * RPB + w * 4 + hfl * 2;
    const int c0  = ch * 32;

    if (tid == 0) s_dead = 0;

    f16x2 wv0[16], wv1[16];
    {
      const float* w0 = W + (size_t)r0 * HDIM + c0;
      const float* w1 = w0 + HDIM;
#pragma unroll
      for (int j = 0; j < 16; ++j) {
        wv0[j] = f16x2{ (f16)w0[2 * j], (f16)w0[2 * j + 1] };
        wv1[j] = f16x2{ (f16)w1[2 * j], (f16)w1[2 * j + 1] };
      }
    }

    for (unsigned t = 1; t <= SEQ; ++t) {
      const int hb = (int)(t & 1) * 544;       // hl buffer for this step
      float x0 = 0.f, x1 = 0.f;
      if (ch == 0) {
        const float* xr = xp + (size_t)(t - 1) * HDIM + r0;
        x0 = xr[0]; x1 = xr[1];
      }

      if (w == 0) {
        const unsigned need = t - 1;
        const unsigned long long* row = pairs + ((t - 1) & 1) * 512 + l * 8;
        unsigned long long u[8];
        bool valid = false;
        {  // fused gate + speculative payload poll
          int g = 0;
          unsigned ready = 16;       // speculate on 1st iter (straggler case)
          for (;;) {
            const bool spec = (ready >= 12);
            if (spec) {
#pragma unroll
              for (int j = 0; j < 8; ++j) u[j] = rd64(row + j);
            }
            unsigned sv = need;
            if (l < 16) sv = rd32(sumR + l * 32);
            unsigned long long miss = __ballot(sv < need);
            if (miss == 0ULL) {
              if (spec) {
                bool ok = true;
#pragma unroll
                for (int j = 0; j < 8; ++j)
                  ok &= ((unsigned)(u[j] >> 32) == need);
                if (__ballot(!ok) == 0ULL) valid = true;
              }
              break;
            }
            ready = 16u - (unsigned)__popcll(miss);
            if (++g > (1 << 20)) { if (l == 0) s_dead = 1; break; }
          }
        }
        if (!valid) {  // residual validated sweep (rare)
          int g = 0;
          for (;;) {
            bool ok = true;
#pragma unroll
            for (int j = 0; j < 8; ++j) u[j] = rd64(row + j);
#pragma unroll
            for (int j = 0; j < 8; ++j)
              ok &= ((unsigned)(u[j] >> 32) == need);
            if (__ballot(!ok) == 0ULL) break;
            if (++g > (1 << 20)) { if (l == 0) s_dead = 1; break; }
          }
        }
        const int base = (l >> 1) * 17 + (l & 1) * 8;
#pragma unroll
        for (int j = 0; j < 8; ++j) hl[hb + base + j] = (unsigned)u[j];
      }
      __syncthreads();                 // barrier A: hl[hb] ready
      if (s_dead) return;

      float s0 = 0.f, s1 = 0.f;
#pragma unroll
      for (int j = 0; j < 16; ++j) {
        f16x2 hv = __builtin_bit_cast(f16x2, hl[hb + ch * 17 + j]);
        s0 = __builtin_amdgcn_fdot2(wv0[j], hv, s0, false);
        s1 = __builtin_amdgcn_fdot2(wv1[j], hv, s1, false);
      }
#pragma unroll
      for (int m = 16; m >= 1; m >>= 1) {
        s0 += __shfl_xor(s0, m, 64);
        s1 += __shfl_xor(s1, m, 64);
      }

      if (ch == 0) {
        // fast tanh: 1 - 2/(e^{2x}+1); |err| ~1e-6 << f16 storage rounding
        float a0 = x0 + s0, a1 = x1 + s1;
        float e0 = __expf(2.f * a0), e1 = __expf(2.f * a1);
        float h0 = 1.f - 2.f * __builtin_amdgcn_rcpf(e0 + 1.f);
        float h1 = 1.f - 2.f * __builtin_amdgcn_rcpf(e1 + 1.f);
        f16x2 hh = { (f16)h0, (f16)h1 };
        unsigned pay = __builtin_bit_cast(unsigned, hh);
        unsigned long long val = ((unsigned long long)t << 32) | (unsigned long long)pay;
        pub64(pairs + (t & 1) * 512 + (r0 >> 1), val);
        pub32((unsigned*)hs + (((size_t)t * HDIM + r0) >> 1), pay);
        // gate published immediately -- no barrier, no vmcnt drain (R16)
        if (tid == 0) pub32(sumR + b * 32, t);
      }

      if ((t & 127u) == 0u) {          // strip boundary (once per 128 steps)
        __syncthreads();               // drains this strip's hs pubs
        if (tid == 0)
          pub32(sumG + (int)((t >> 7) - 1) * 16 + b, t);
      }
    }
    return;
  }

  // ================= persistent head-GEMM worker =================
  // tile 128x128, 16 waves, wave-tile 32x32 (2x2 16x16 frags)
  const int g  = blockIdx.x - NBLK;           // 0..239
  const int wm = (wv >> 2) * 32;
  const int wn = (wv & 3) * 32;
  const int half = tid >> 9;                  // 0: stage A, 1: stage B
  const int i    = tid & 511;
  const int srow = i >> 2;
  const int soff = (i & 3) * 8;

  for (int ti = g; ti < NTIL; ti += NGWK) {
    const int mt = ti / 250, nt = ti % 250;
    const unsigned S = (unsigned)(mt * 128 + 128);

    if (wv == 0) {                     // sleep-throttled strip gate (>=)
      const unsigned* sp = sumG + mt * 16 + l;
      int gu = 0;
      for (;;) {
        unsigned sv = S;
        if (l < 16) sv = rd32(sp);
        if (__ballot(sv < S) == 0ULL) break;
        __builtin_amdgcn_s_sleep(32);
        if (++gu > (1 << 21)) break;   // bounded; proceed (absmax will flag)
      }
    }
    __syncthreads();

    const f16* A = hs + (size_t)(mt * 128 + 1) * HDIM;   // timesteps mt*128+1..+128
    const f16* B = Wfc + (size_t)nt * 128 * HDIM;
    const f16* sbase = (half ? B : A) + (size_t)srow * HDIM + soff;

    f32x4 acc[2][2] = {};

    for (int kt = 0; kt < HDIM; kt += 32) {
      uint4 r = *(const uint4*)(sbase + kt);
      __syncthreads();                 // prev iter's ds reads done
      *(uint4*)((half ? lsB : lsA) + i * 8) = r;
      __syncthreads();

      f16x8 af[2], bf[2];
#pragma unroll
      for (int m = 0; m < 2; ++m)
        af[m] = *(const f16x8*)(lsA + (wm + m * 16 + (l & 15)) * 32 + (l >> 4) * 8);
#pragma unroll
      for (int n = 0; n < 2; ++n)
        bf[n] = *(const f16x8*)(lsB + (wn + n * 16 + (l & 15)) * 32 + (l >> 4) * 8);
#pragma unroll
      for (int m = 0; m < 2; ++m)
#pragma unroll
        for (int n = 0; n < 2; ++n)
          acc[m][n] = __builtin_amdgcn_mfma_f32_16x16x32_f16(af[m], bf[n], acc[m][n], 0, 0, 0);
    }

#pragma unroll
    for (int n = 0; n < 2; ++n) {
      int col = nt * 128 + wn + n * 16 + (l & 15);
      float bv = bfc[col];
#pragma unroll
      for (int m = 0; m < 2; ++m) {
#pragma unroll
        for (int j = 0; j < 4; ++j) {
          int row = mt * 128 + wm + m * 16 + (l >> 4) * 4 + j;
          out[(size_t)row * 32000 + col] = acc[m][n][j] + bv;
        }
      }
    }
    __syncthreads();                   // all reads done before next tile stages
  }
}

// ---------------- launch ----------------
extern "C" void kernel_launch(void* const* d_in, const int* in_sizes, int n_in,
                              void* d_out, int out_size, void* d_ws, size_t ws_size,
                              hipStream_t stream) {
  const float* x    = (const float*)d_in[0];
  const float* W_ih = (const float*)d_in[1];
  const float* W_hh = (const float*)d_in[2];
  const float* b_ih = (const float*)d_in[3];
  const float* b_hh = (const float*)d_in[4];
  const float* W_fc = (const float*)d_in[5];
  const float* b_fc = (const float*)d_in[6];
  float* out = (float*)d_out;                  // [2048][32000] f32

  char* ws = (char*)d_ws;
  unsigned long long* pairs = (unsigned long long*)ws;       // 2*512*8 = 8,192
  unsigned* sumR  = (unsigned*)(ws + 8192);                  // 16*32*4 = 2,048
  unsigned* sumG  = (unsigned*)(ws + 10240);                 // 16*16*4 = 1,024
  f16*   hs16  = (f16*)(ws + 16384);                         // 4,196,352
  float* xp    = (float*)(ws + 4212736);                     // 8,388,608
  f16*   x16   = (f16*)(ws + 12601344);                      // 4,194,304
  f16*   wih16 = (f16*)(ws + 16795648);                      // 2,097,152
  f16*   wfc16 = (f16*)(ws + 18892800);                      // 65,536,000
  float* bsum  = (float*)(ws + 84428800);                    // 4,096 (total ~84.4MB)

  k_clear<<<4, 256, 0, stream>>>(pairs, 2 * 512, sumR, 16 * 32, sumG, 16 * 16);
  k_cvt<<<1024, 256, 0, stream>>>(x, x16, 2048 * 1024 / 4);
  k_cvt<<<1024, 256, 0, stream>>>(W_ih, wih16, 1024 * 1024 / 4);
  k_cvt<<<2048, 256, 0, stream>>>(W_fc, wfc16, 32000 * 1024 / 4);
  k_bias<<<4, 256, 0, stream>>>(b_ih, b_hh, bsum);

  // xp = x @ W_ih^T + (b_ih + b_hh)
  k_gemm<<<dim3(8, 16), 256, 0, stream>>>(x16, wih16, bsum, xp, 1024);

  // fused: recurrence + head GEMM overlap
  k_main<<<NBLK + NGWK, 1024, 0, stream>>>(W_hh, xp, pairs, sumR, sumG, hs16,
                                           wfc16, b_fc, out);
}

// Round 18
// 4151.969 us; speedup vs baseline: 1.1491x; 1.1491x over previous
//
#include <hip/hip_runtime.h>
#include <math.h>

typedef _Float16 f16;
typedef f16 f16x2 __attribute__((ext_vector_type(2)));
typedef f16 f16x4 __attribute__((ext_vector_type(4)));
typedef f16 f16x8 __attribute__((ext_vector_type(8)));
typedef float f32x4 __attribute__((ext_vector_type(4)));

#define HDIM 1024
#define SEQ  2048
#define NBLK 16    // recurrence blocks
#define NGWK 240   // persistent gemm worker blocks
#define RPB  64    // rows of W_hh per recurrence block
#define NTIL 4000  // 16 M-strips x 250 N-tiles

// ---------------- merged prologue: clear + converts + bias ----------------
// One kernel replaces k_clear + 3x k_cvt + k_bias (saves 4 graph launches and
// lets the three streaming converts share BW). pairs ring slot 0 =
// (tag=0,payload=0) doubles as h_0 = 0; sumR/sumG cleared (kills stale tags
// from replays / 0xAA poison).
__global__ void k_prep(const float* __restrict__ x,    f16* __restrict__ x16,
                       const float* __restrict__ Wih,  f16* __restrict__ wih16,
                       const float* __restrict__ Wfc,  f16* __restrict__ wfc16,
                       const float* __restrict__ bih,  const float* __restrict__ bhh,
                       float* __restrict__ bsum,
                       unsigned long long* __restrict__ pairs,
                       unsigned* __restrict__ sumR, unsigned* __restrict__ sumG) {
  const int stride = gridDim.x * blockDim.x;
  const int id = blockIdx.x * blockDim.x + threadIdx.x;
  for (int i = id; i < 2 * 512; i += stride) pairs[i] = 0ULL;
  for (int i = id; i < 16 * 32; i += stride) sumR[i] = 0u;
  for (int i = id; i < 16 * 16; i += stride) sumG[i] = 0u;
  if (id < HDIM) bsum[id] = bih[id] + bhh[id];
  for (int i = id; i < 2048 * 1024 / 4; i += stride) {
    float4 v = ((const float4*)x)[i];
    ((f16x4*)x16)[i] = f16x4{ (f16)v.x, (f16)v.y, (f16)v.z, (f16)v.w };
  }
  for (int i = id; i < 1024 * 1024 / 4; i += stride) {
    float4 v = ((const float4*)Wih)[i];
    ((f16x4*)wih16)[i] = f16x4{ (f16)v.x, (f16)v.y, (f16)v.z, (f16)v.w };
  }
  for (int i = id; i < 32000 * 1024 / 4; i += stride) {
    float4 v = ((const float4*)Wfc)[i];
    ((f16x4*)wfc16)[i] = f16x4{ (f16)v.x, (f16)v.y, (f16)v.z, (f16)v.w };
  }
}

// ---------------- standalone 256-thr GEMM (xp projection only) ----------------
__global__ __launch_bounds__(256) void k_gemm(
    const f16* __restrict__ A, const f16* __restrict__ B,
    const float* __restrict__ bias, float* __restrict__ C, int N)
{
  const int K = 1024;
  __shared__ __align__(16) f16 lsA[128 * 32];
  __shared__ __align__(16) f16 lsB[128 * 32];
  const int tid = threadIdx.x;
  const int l   = tid & 63;
  const int wv  = tid >> 6;
  const int mb  = blockIdx.y * 128;
  const int nb  = blockIdx.x * 128;
  const int wm  = (wv >> 1) * 64;
  const int wn  = (wv & 1) * 64;

  f32x4 acc[4][4] = {};

  for (int kt = 0; kt < K; kt += 32) {
    uint4 ra[2], rb[2];
#pragma unroll
    for (int i = 0; i < 2; ++i) {
      int c = tid + i * 256;
      int row = c >> 2, off = (c & 3) * 8;
      ra[i] = *(const uint4*)(A + (size_t)(mb + row) * K + kt + off);
      rb[i] = *(const uint4*)(B + (size_t)(nb + row) * K + kt + off);
    }
    __syncthreads();
#pragma unroll
    for (int i = 0; i < 2; ++i) {
      int c = tid + i * 256;
      *(uint4*)(lsA + c * 8) = ra[i];
      *(uint4*)(lsB + c * 8) = rb[i];
    }
    __syncthreads();

    f16x8 af[4], bf[4];
#pragma unroll
    for (int m = 0; m < 4; ++m)
      af[m] = *(const f16x8*)(lsA + (wm + m * 16 + (l & 15)) * 32 + (l >> 4) * 8);
#pragma unroll
    for (int n = 0; n < 4; ++n)
      bf[n] = *(const f16x8*)(lsB + (wn + n * 16 + (l & 15)) * 32 + (l >> 4) * 8);
#pragma unroll
    for (int m = 0; m < 4; ++m)
#pragma unroll
      for (int n = 0; n < 4; ++n)
        acc[m][n] = __builtin_amdgcn_mfma_f32_16x16x32_f16(af[m], bf[n], acc[m][n], 0, 0, 0);
  }

#pragma unroll
  for (int n = 0; n < 4; ++n) {
    int col = nb + wn + n * 16 + (l & 15);
    float bv = bias[col];
#pragma unroll
    for (int m = 0; m < 4; ++m) {
#pragma unroll
      for (int j = 0; j < 4; ++j) {
        int row = mb + wm + m * 16 + (l >> 4) * 4 + j;
        C[(size_t)row * N + col] = acc[m][n][j] + bv;
      }
    }
  }
}

// ---- comm primitives (proven): WRITER = agent-scope atomic RMW (exchange),
// executes AT the MALL, leaves line dirty-resident (R6: plain sc1 stores
// write through + invalidate -> HBM poll misses; R10/R15: wg-scope and
// no-sc1-asm L2 paths give no usable cross-block visibility). READER =
// agent-scope atomic LOAD (R14: parity with RMW reader, less RMW-unit
// pressure). Tag-in-data absorbs reorder; staleness only delays; no fences.
__device__ __forceinline__ void pub64(unsigned long long* p, unsigned long long v) {
  (void)__hip_atomic_exchange(p, v, __ATOMIC_RELAXED, __HIP_MEMORY_SCOPE_AGENT);
}
__device__ __forceinline__ void pub32(unsigned* p, unsigned v) {
  (void)__hip_atomic_exchange(p, v, __ATOMIC_RELAXED, __HIP_MEMORY_SCOPE_AGENT);
}
__device__ __forceinline__ unsigned long long rd64(const unsigned long long* p) {
  return __hip_atomic_load(p, __ATOMIC_RELAXED, __HIP_MEMORY_SCOPE_AGENT);
}
__device__ __forceinline__ unsigned rd32(const unsigned* p) {
  return __hip_atomic_load(p, __ATOMIC_RELAXED, __HIP_MEMORY_SCOPE_AGENT);
}

// ---------------- FUSED: recurrence (blocks 0-15) + head GEMM (16-255) -------
// Grid = 256 x 1024 thr -> <=1 block/CU -> all co-resident (G16-safe).
// R16 protocol (best measured: 1.94us/step):
//  * gate: 16 persistent lines sumR[b*32] (1 publisher + 16 pollers each);
//    monotone tags, poll >=.
//  * payload: 2-slot ring pairs[2][512], tag<<32|f16x2 words (MALL-resident;
//    overwrite safe by +/-1 lockstep; embedded tags validate exactness).
//  * NO barrier B: gate tag published immediately after tid0's payload pubs
//    (no vmcnt drain). Late sibling payloads absorbed by sweep validation.
//  * hl DOUBLE-BUFFERED by step parity (overwrite of hl[par] at t+2 requires
//    sweep(t+1), which requires our payloads of t+1, published only after
//    barrier A(t+1) -- after the step-t hl reads. Induction closes).
//  * sumG per-STRIP, published once per 128 steps after a strip-boundary
//    __syncthreads (drains that strip's hs pubs; off critical path).
__global__ __launch_bounds__(1024, 4) void k_main(
    const float* __restrict__ W,              // W_hh f32 [H][H]
    const float* __restrict__ xp,             // [SEQ][H] f32
    unsigned long long* __restrict__ pairs,   // [2][512] ring: tag<<32|f16x2
    unsigned* __restrict__ sumR,              // [16*32] persistent gate tags
    unsigned* __restrict__ sumG,              // [16 strips][16 blocks]
    f16* __restrict__ hs,                     // [(SEQ+1)][H] clean copy
    const f16* __restrict__ Wfc,              // [32000][1024] f16
    const float* __restrict__ bfc,            // [32000]
    float* __restrict__ out)                  // [2048][32000]
{
  __shared__ unsigned hl[2 * 544]; // DOUBLE-BUFFERED bounce (17-stride swizzle)
  __shared__ int s_dead;
  __shared__ __align__(16) f16 lsA[128 * 32];  // gemm tiles
  __shared__ __align__(16) f16 lsB[128 * 32];

  const int tid = threadIdx.x;
  const int l   = tid & 63;
  const int wv  = tid >> 6;

  if (blockIdx.x < NBLK) {
    // ================= recurrence =================
    const int b   = blockIdx.x;
    const int w   = wv;
    const int hfl = l >> 5;
    const int ch  = l & 31;
    const int r0  = b * RPB + w * 4 + hfl * 2;
    const int c0  = ch * 32;

    if (tid == 0) s_dead = 0;

    f16x2 wv0[16], wv1[16];
    {
      const float* w0 = W + (size_t)r0 * HDIM + c0;
      const float* w1 = w0 + HDIM;
#pragma unroll
      for (int j = 0; j < 16; ++j) {
        wv0[j] = f16x2{ (f16)w0[2 * j], (f16)w0[2 * j + 1] };
        wv1[j] = f16x2{ (f16)w1[2 * j], (f16)w1[2 * j + 1] };
      }
    }

    for (unsigned t = 1; t <= SEQ; ++t) {
      const int hb = (int)(t & 1) * 544;       // hl buffer for this step
      float x0 = 0.f, x1 = 0.f;
      if (ch == 0) {
        const float* xr = xp + (size_t)(t - 1) * HDIM + r0;
        x0 = xr[0]; x1 = xr[1];
      }

      if (w == 0) {
        const unsigned need = t - 1;
        {  // gate: lane l polls block l's PERSISTENT tag line (monotone >=)
          int g = 0;
          for (;;) {
            unsigned sv = need;
            if (l < 16) sv = rd32(sumR + l * 32);
            if (__ballot(sv < need) == 0ULL) break;
            if (++g > (1 << 20)) { if (l == 0) s_dead = 1; break; }
          }
        }
        {  // tag-validated payload sweep over ring slot (t-1)&1
          const unsigned long long* row = pairs + ((t - 1) & 1) * 512 + l * 8;
          unsigned long long u[8];
          int g = 0;
          for (;;) {
            bool ok = true;
#pragma unroll
            for (int j = 0; j < 8; ++j) u[j] = rd64(row + j);
#pragma unroll
            for (int j = 0; j < 8; ++j)
              ok &= ((unsigned)(u[j] >> 32) == (t - 1));
            if (__ballot(!ok) == 0ULL) break;
            if (++g > (1 << 20)) { if (l == 0) s_dead = 1; break; }
          }
          const int base = (l >> 1) * 17 + (l & 1) * 8;
#pragma unroll
          for (int j = 0; j < 8; ++j) hl[hb + base + j] = (unsigned)u[j];
        }
      }
      __syncthreads();                 // barrier A: hl[hb] ready
      if (s_dead) return;

      float s0 = 0.f, s1 = 0.f;
#pragma unroll
      for (int j = 0; j < 16; ++j) {
        f16x2 hv = __builtin_bit_cast(f16x2, hl[hb + ch * 17 + j]);
        s0 = __builtin_amdgcn_fdot2(wv0[j], hv, s0, false);
        s1 = __builtin_amdgcn_fdot2(wv1[j], hv, s1, false);
      }
#pragma unroll
      for (int m = 16; m >= 1; m >>= 1) {
        s0 += __shfl_xor(s0, m, 64);
        s1 += __shfl_xor(s1, m, 64);
      }

      if (ch == 0) {
        // fast tanh: 1 - 2/(e^{2x}+1); |err| ~1e-6 << f16 storage rounding
        float a0 = x0 + s0, a1 = x1 + s1;
        float e0 = __expf(2.f * a0), e1 = __expf(2.f * a1);
        float h0 = 1.f - 2.f * __builtin_amdgcn_rcpf(e0 + 1.f);
        float h1 = 1.f - 2.f * __builtin_amdgcn_rcpf(e1 + 1.f);
        f16x2 hh = { (f16)h0, (f16)h1 };
        unsigned pay = __builtin_bit_cast(unsigned, hh);
        unsigned long long val = ((unsigned long long)t << 32) | (unsigned long long)pay;
        pub64(pairs + (t & 1) * 512 + (r0 >> 1), val);
        pub32((unsigned*)hs + (((size_t)t * HDIM + r0) >> 1), pay);
        // gate published immediately -- no barrier, no vmcnt drain
        if (tid == 0) pub32(sumR + b * 32, t);
      }

      if ((t & 127u) == 0u) {          // strip boundary (once per 128 steps)
        __syncthreads();               // drains this strip's hs pubs
        if (tid == 0)
          pub32(sumG + (int)((t >> 7) - 1) * 16 + b, t);
      }
    }
    return;
  }

  // ================= persistent head-GEMM worker =================
  // tile 128x128, 16 waves, wave-tile 32x32 (2x2 16x16 frags)
  const int g  = blockIdx.x - NBLK;           // 0..239
  const int wm = (wv >> 2) * 32;
  const int wn = (wv & 3) * 32;
  const int half = tid >> 9;                  // 0: stage A, 1: stage B
  const int i    = tid & 511;
  const int srow = i >> 2;
  const int soff = (i & 3) * 8;

  for (int ti = g; ti < NTIL; ti += NGWK) {
    const int mt = ti / 250, nt = ti % 250;
    const unsigned S = (unsigned)(mt * 128 + 128);

    if (wv == 0) {                     // sleep-throttled strip gate (>=)
      const unsigned* sp = sumG + mt * 16 + l;
      int gu = 0;
      for (;;) {
        unsigned sv = S;
        if (l < 16) sv = rd32(sp);
        if (__ballot(sv < S) == 0ULL) break;
        __builtin_amdgcn_s_sleep(32);
        if (++gu > (1 << 21)) break;   // bounded; proceed (absmax will flag)
      }
    }
    __syncthreads();

    const f16* A = hs + (size_t)(mt * 128 + 1) * HDIM;   // timesteps mt*128+1..+128
    const f16* B = Wfc + (size_t)nt * 128 * HDIM;
    const f16* sbase = (half ? B : A) + (size_t)srow * HDIM + soff;

    f32x4 acc[2][2] = {};

    for (int kt = 0; kt < HDIM; kt += 32) {
      uint4 r = *(const uint4*)(sbase + kt);
      __syncthreads();                 // prev iter's ds reads done
      *(uint4*)((half ? lsB : lsA) + i * 8) = r;
      __syncthreads();

      f16x8 af[2], bf[2];
#pragma unroll
      for (int m = 0; m < 2; ++m)
        af[m] = *(const f16x8*)(lsA + (wm + m * 16 + (l & 15)) * 32 + (l >> 4) * 8);
#pragma unroll
      for (int n = 0; n < 2; ++n)
        bf[n] = *(const f16x8*)(lsB + (wn + n * 16 + (l & 15)) * 32 + (l >> 4) * 8);
#pragma unroll
      for (int m = 0; m < 2; ++m)
#pragma unroll
        for (int n = 0; n < 2; ++n)
          acc[m][n] = __builtin_amdgcn_mfma_f32_16x16x32_f16(af[m], bf[n], acc[m][n], 0, 0, 0);
    }

#pragma unroll
    for (int n = 0; n < 2; ++n) {
      int col = nt * 128 + wn + n * 16 + (l & 15);
      float bv = bfc[col];
#pragma unroll
      for (int m = 0; m < 2; ++m) {
#pragma unroll
        for (int j = 0; j < 4; ++j) {
          int row = mt * 128 + wm + m * 16 + (l >> 4) * 4 + j;
          out[(size_t)row * 32000 + col] = acc[m][n][j] + bv;
        }
      }
    }
    __syncthreads();                   // all reads done before next tile stages
  }
}

// ---------------- launch ----------------
extern "C" void kernel_launch(void* const* d_in, const int* in_sizes, int n_in,
                              void* d_out, int out_size, void* d_ws, size_t ws_size,
                              hipStream_t stream) {
  const float* x    = (const float*)d_in[0];
  const float* W_ih = (const float*)d_in[1];
  const float* W_hh = (const float*)d_in[2];
  const float* b_ih = (const float*)d_in[3];
  const float* b_hh = (const float*)d_in[4];
  const float* W_fc = (const float*)d_in[5];
  const float* b_fc = (const float*)d_in[6];
  float* out = (float*)d_out;                  // [2048][32000] f32

  char* ws = (char*)d_ws;
  unsigned long long* pairs = (unsigned long long*)ws;       // 2*512*8 = 8,192
  unsigned* sumR  = (unsigned*)(ws + 8192);                  // 16*32*4 = 2,048
  unsigned* sumG  = (unsigned*)(ws + 10240);                 // 16*16*4 = 1,024
  f16*   hs16  = (f16*)(ws + 16384);                         // 4,196,352
  float* xp    = (float*)(ws + 4212736);                     // 8,388,608
  f16*   x16   = (f16*)(ws + 12601344);                      // 4,194,304
  f16*   wih16 = (f16*)(ws + 16795648);                      // 2,097,152
  f16*   wfc16 = (f16*)(ws + 18892800);                      // 65,536,000
  float* bsum  = (float*)(ws + 84428800);                    // 4,096 (total ~84.4MB)

  // merged prologue (was 5 kernels)
  k_prep<<<2048, 256, 0, stream>>>(x, x16, W_ih, wih16, W_fc, wfc16,
                                   b_ih, b_hh, bsum, pairs, sumR, sumG);

  // xp = x @ W_ih^T + (b_ih + b_hh)
  k_gemm<<<dim3(8, 16), 256, 0, stream>>>(x16, wih16, bsum, xp, 1024);

  // fused: recurrence + head GEMM overlap
  k_main<<<NBLK + NGWK, 1024, 0, stream>>>(W_hh, xp, pairs, sumR, sumG, hs16,
                                           wfc16, b_fc, out);
}

// Round 19
// 4018.151 us; speedup vs baseline: 1.1874x; 1.0333x over previous
//
#include <hip/hip_runtime.h>
#include <math.h>

typedef _Float16 f16;
typedef f16 f16x2 __attribute__((ext_vector_type(2)));
typedef f16 f16x4 __attribute__((ext_vector_type(4)));
typedef f16 f16x8 __attribute__((ext_vector_type(8)));
typedef float f32x4 __attribute__((ext_vector_type(4)));

#define HDIM 1024
#define SEQ  2048
#define NBLK 16    // recurrence blocks
#define NGWK 240   // persistent gemm worker blocks
#define RPB  64    // rows of W_hh per recurrence block
#define NTIL 4000  // 16 M-strips x 250 N-tiles

// ---------------- clear comm arrays ----------------
__global__ void k_clear(unsigned long long* __restrict__ p, int n,
                        unsigned* __restrict__ sR, int nr,
                        unsigned* __restrict__ sG, int ng) {
  int stride = gridDim.x * blockDim.x;
  int id = blockIdx.x * blockDim.x + threadIdx.x;
  for (int i = id; i < n; i += stride) p[i] = 0ULL;
  for (int i = id; i < nr; i += stride) sR[i] = 0u;
  for (int i = id; i < ng; i += stride) sG[i] = 0u;
}

// ---------------- f32 -> f16 convert (vec4, grid-stride) ----------------
__global__ void k_cvt(const float* __restrict__ in, f16* __restrict__ out, int n4) {
  int stride = gridDim.x * blockDim.x;
  for (int i = blockIdx.x * blockDim.x + threadIdx.x; i < n4; i += stride) {
    float4 v = ((const float4*)in)[i];
    f16x4 o = { (f16)v.x, (f16)v.y, (f16)v.z, (f16)v.w };
    ((f16x4*)out)[i] = o;
  }
}

__global__ void k_bias(const float* __restrict__ a, const float* __restrict__ b,
                       float* __restrict__ o) {
  int i = blockIdx.x * blockDim.x + threadIdx.x;
  if (i < HDIM) o[i] = a[i] + b[i];
}

// ---------------- standalone 256-thr GEMM (xp projection only) ----------------
__global__ __launch_bounds__(256) void k_gemm(
    const f16* __restrict__ A, const f16* __restrict__ B,
    const float* __restrict__ bias, float* __restrict__ C, int N)
{
  const int K = 1024;
  __shared__ __align__(16) f16 lsA[128 * 32];
  __shared__ __align__(16) f16 lsB[128 * 32];
  const int tid = threadIdx.x;
  const int l   = tid & 63;
  const int wv  = tid >> 6;
  const int mb  = blockIdx.y * 128;
  const int nb  = blockIdx.x * 128;
  const int wm  = (wv >> 1) * 64;
  const int wn  = (wv & 1) * 64;

  f32x4 acc[4][4] = {};

  for (int kt = 0; kt < K; kt += 32) {
    uint4 ra[2], rb[2];
#pragma unroll
    for (int i = 0; i < 2; ++i) {
      int c = tid + i * 256;
      int row = c >> 2, off = (c & 3) * 8;
      ra[i] = *(const uint4*)(A + (size_t)(mb + row) * K + kt + off);
      rb[i] = *(const uint4*)(B + (size_t)(nb + row) * K + kt + off);
    }
    __syncthreads();
#pragma unroll
    for (int i = 0; i < 2; ++i) {
      int c = tid + i * 256;
      *(uint4*)(lsA + c * 8) = ra[i];
      *(uint4*)(lsB + c * 8) = rb[i];
    }
    __syncthreads();

    f16x8 af[4], bf[4];
#pragma unroll
    for (int m = 0; m < 4; ++m)
      af[m] = *(const f16x8*)(lsA + (wm + m * 16 + (l & 15)) * 32 + (l >> 4) * 8);
#pragma unroll
    for (int n = 0; n < 4; ++n)
      bf[n] = *(const f16x8*)(lsB + (wn + n * 16 + (l & 15)) * 32 + (l >> 4) * 8);
#pragma unroll
    for (int m = 0; m < 4; ++m)
#pragma unroll
      for (int n = 0; n < 4; ++n)
        acc[m][n] = __builtin_amdgcn_mfma_f32_16x16x32_f16(af[m], bf[n], acc[m][n], 0, 0, 0);
  }

#pragma unroll
  for (int n = 0; n < 4; ++n) {
    int col = nb + wn + n * 16 + (l & 15);
    float bv = bias[col];
#pragma unroll
    for (int m = 0; m < 4; ++m) {
#pragma unroll
      for (int j = 0; j < 4; ++j) {
        int row = mb + wm + m * 16 + (l >> 4) * 4 + j;
        C[(size_t)row * N + col] = acc[m][n][j] + bv;
      }
    }
  }
}

// ---- comm primitives (proven): WRITER = agent-scope atomic RMW (exchange),
// executes AT the MALL, leaves line dirty-resident (R6: plain sc1 stores
// write through + invalidate -> HBM poll misses; R10/R15: wg-scope and
// no-sc1-asm L2 paths give no usable cross-block visibility). READER =
// agent-scope atomic LOAD (R14: parity with RMW reader, less RMW-unit
// pressure). Tag-in-data absorbs reorder; staleness only delays; no fences.
__device__ __forceinline__ void pub64(unsigned long long* p, unsigned long long v) {
  (void)__hip_atomic_exchange(p, v, __ATOMIC_RELAXED, __HIP_MEMORY_SCOPE_AGENT);
}
__device__ __forceinline__ void pub32(unsigned* p, unsigned v) {
  (void)__hip_atomic_exchange(p, v, __ATOMIC_RELAXED, __HIP_MEMORY_SCOPE_AGENT);
}
__device__ __forceinline__ unsigned long long rd64(const unsigned long long* p) {
  return __hip_atomic_load(p, __ATOMIC_RELAXED, __HIP_MEMORY_SCOPE_AGENT);
}
__device__ __forceinline__ unsigned rd32(const unsigned* p) {
  return __hip_atomic_load(p, __ATOMIC_RELAXED, __HIP_MEMORY_SCOPE_AGENT);
}

// ---------------- FUSED: recurrence (blocks 0-15) + head GEMM (16-255) -------
// Grid = 256 x 1024 thr -> <=1 block/CU -> all co-resident (G16-safe).
// R16 protocol (best measured: 1.94us/step):
//  * gate: 16 persistent lines sumR[b*32] (1 publisher + 16 pollers each);
//    monotone tags, poll >=.
//  * payload: 2-slot ring pairs[2][512], tag<<32|f16x2 words (MALL-resident;
//    overwrite safe by +/-1 lockstep; embedded tags validate exactness).
//  * NO barrier B: gate tag published immediately after tid0's payload pubs
//    (no vmcnt drain). Late sibling payloads absorbed by sweep validation.
//  * hl DOUBLE-BUFFERED by step parity (overwrite of hl[par] at t+2 requires
//    sweep(t+1), which requires our payloads of t+1, published only after
//    barrier A(t+1) -- after the step-t hl reads. Induction closes).
//  * sumG per-STRIP, published once per 128 steps after a strip-boundary
//    __syncthreads (drains that strip's hs pubs; off critical path).
__global__ __launch_bounds__(1024, 4) void k_main(
    const float* __restrict__ W,              // W_hh f32 [H][H]
    const float* __restrict__ xp,             // [SEQ][H] f32
    unsigned long long* __restrict__ pairs,   // [2][512] ring: tag<<32|f16x2
    unsigned* __restrict__ sumR,              // [16*32] persistent gate tags
    unsigned* __restrict__ sumG,              // [16 strips][16 blocks]
    f16* __restrict__ hs,                     // [(SEQ+1)][H] clean copy
    const f16* __restrict__ Wfc,              // [32000][1024] f16
    const float* __restrict__ bfc,            // [32000]
    float* __restrict__ out)                  // [2048][32000]
{
  __shared__ unsigned hl[2 * 544]; // DOUBLE-BUFFERED bounce (17-stride swizzle)
  __shared__ int s_dead;
  __shared__ __align__(16) f16 lsA[128 * 32];  // gemm tiles
  __shared__ __align__(16) f16 lsB[128 * 32];

  const int tid = threadIdx.x;
  const int l   = tid & 63;
  const int wv  = tid >> 6;

  if (blockIdx.x < NBLK) {
    // ================= recurrence =================
    const int b   = blockIdx.x;
    const int w   = wv;
    const int hfl = l >> 5;
    const int ch  = l & 31;
    const int r0  = b * RPB + w * 4 + hfl * 2;
    const int c0  = ch * 32;

    if (tid == 0) s_dead = 0;

    f16x2 wv0[16], wv1[16];
    {
      const float* w0 = W + (size_t)r0 * HDIM + c0;
      const float* w1 = w0 + HDIM;
#pragma unroll
      for (int j = 0; j < 16; ++j) {
        wv0[j] = f16x2{ (f16)w0[2 * j], (f16)w0[2 * j + 1] };
        wv1[j] = f16x2{ (f16)w1[2 * j], (f16)w1[2 * j + 1] };
      }
    }

    for (unsigned t = 1; t <= SEQ; ++t) {
      const int hb = (int)(t & 1) * 544;       // hl buffer for this step
      float x0 = 0.f, x1 = 0.f;
      if (ch == 0) {
        const float* xr = xp + (size_t)(t - 1) * HDIM + r0;
        x0 = xr[0]; x1 = xr[1];
      }

      if (w == 0) {
        const unsigned need = t - 1;
        {  // gate: lane l polls block l's PERSISTENT tag line (monotone >=)
          int g = 0;
          for (;;) {
            unsigned sv = need;
            if (l < 16) sv = rd32(sumR + l * 32);
            if (__ballot(sv < need) == 0ULL) break;
            if (++g > (1 << 20)) { if (l == 0) s_dead = 1; break; }
          }
        }
        {  // tag-validated payload sweep over ring slot (t-1)&1
          const unsigned long long* row = pairs + ((t - 1) & 1) * 512 + l * 8;
          unsigned long long u[8];
          int g = 0;
          for (;;) {
            bool ok = true;
#pragma unroll
            for (int j = 0; j < 8; ++j) u[j] = rd64(row + j);
#pragma unroll
            for (int j = 0; j < 8; ++j)
              ok &= ((unsigned)(u[j] >> 32) == (t - 1));
            if (__ballot(!ok) == 0ULL) break;
            if (++g > (1 << 20)) { if (l == 0) s_dead = 1; break; }
          }
          const int base = (l >> 1) * 17 + (l & 1) * 8;
#pragma unroll
          for (int j = 0; j < 8; ++j) hl[hb + base + j] = (unsigned)u[j];
        }
      }
      __syncthreads();                 // barrier A: hl[hb] ready
      if (s_dead) return;

      float s0 = 0.f, s1 = 0.f;
#pragma unroll
      for (int j = 0; j < 16; ++j) {
        f16x2 hv = __builtin_bit_cast(f16x2, hl[hb + ch * 17 + j]);
        s0 = __builtin_amdgcn_fdot2(wv0[j], hv, s0, false);
        s1 = __builtin_amdgcn_fdot2(wv1[j], hv, s1, false);
      }
#pragma unroll
      for (int m = 16; m >= 1; m >>= 1) {
        s0 += __shfl_xor(s0, m, 64);
        s1 += __shfl_xor(s1, m, 64);
      }

      if (ch == 0) {
        // fast tanh: 1 - 2/(e^{2x}+1); |err| ~1e-6 << f16 storage rounding
        float a0 = x0 + s0, a1 = x1 + s1;
        float e0 = __expf(2.f * a0), e1 = __expf(2.f * a1);
        float h0 = 1.f - 2.f * __builtin_amdgcn_rcpf(e0 + 1.f);
        float h1 = 1.f - 2.f * __builtin_amdgcn_rcpf(e1 + 1.f);
        f16x2 hh = { (f16)h0, (f16)h1 };
        unsigned pay = __builtin_bit_cast(unsigned, hh);
        unsigned long long val = ((unsigned long long)t << 32) | (unsigned long long)pay;
        pub64(pairs + (t & 1) * 512 + (r0 >> 1), val);
        pub32((unsigned*)hs + (((size_t)t * HDIM + r0) >> 1), pay);
        // gate published immediately -- no barrier, no vmcnt drain
        if (tid == 0) pub32(sumR + b * 32, t);
      }

      if ((t & 127u) == 0u) {          // strip boundary (once per 128 steps)
        __syncthreads();               // drains this strip's hs pubs
        if (tid == 0)
          pub32(sumG + (int)((t >> 7) - 1) * 16 + b, t);
      }
    }
    return;
  }

  // ================= persistent head-GEMM worker =================
  // tile 128x128, 16 waves, wave-tile 32x32 (2x2 16x16 frags)
  const int g  = blockIdx.x - NBLK;           // 0..239
  const int wm = (wv >> 2) * 32;
  const int wn = (wv & 3) * 32;
  const int half = tid >> 9;                  // 0: stage A, 1: stage B
  const int i    = tid & 511;
  const int srow = i >> 2;
  const int soff = (i & 3) * 8;

  for (int ti = g; ti < NTIL; ti += NGWK) {
    const int mt = ti / 250, nt = ti % 250;
    const unsigned S = (unsigned)(mt * 128 + 128);

    if (wv == 0) {                     // sleep-throttled strip gate (>=)
      const unsigned* sp = sumG + mt * 16 + l;
      int gu = 0;
      for (;;) {
        unsigned sv = S;
        if (l < 16) sv = rd32(sp);
        if (__ballot(sv < S) == 0ULL) break;
        __builtin_amdgcn_s_sleep(32);
        if (++gu > (1 << 21)) break;   // bounded; proceed (absmax will flag)
      }
    }
    __syncthreads();

    const f16* A = hs + (size_t)(mt * 128 + 1) * HDIM;   // timesteps mt*128+1..+128
    const f16* B = Wfc + (size_t)nt * 128 * HDIM;
    const f16* sbase = (half ? B : A) + (size_t)srow * HDIM + soff;

    f32x4 acc[2][2] = {};

    for (int kt = 0; kt < HDIM; kt += 32) {
      uint4 r = *(const uint4*)(sbase + kt);
      __syncthreads();                 // prev iter's ds reads done
      *(uint4*)((half ? lsB : lsA) + i * 8) = r;
      __syncthreads();

      f16x8 af[2], bf[2];
#pragma unroll
      for (int m = 0; m < 2; ++m)
        af[m] = *(const f16x8*)(lsA + (wm + m * 16 + (l & 15)) * 32 + (l >> 4) * 8);
#pragma unroll
      for (int n = 0; n < 2; ++n)
        bf[n] = *(const f16x8*)(lsB + (wn + n * 16 + (l & 15)) * 32 + (l >> 4) * 8);
#pragma unroll
      for (int m = 0; m < 2; ++m)
#pragma unroll
        for (int n = 0; n < 2; ++n)
          acc[m][n] = __builtin_amdgcn_mfma_f32_16x16x32_f16(af[m], bf[n], acc[m][n], 0, 0, 0);
    }

#pragma unroll
    for (int n = 0; n < 2; ++n) {
      int col = nt * 128 + wn + n * 16 + (l & 15);
      float bv = bfc[col];
#pragma unroll
      for (int m = 0; m < 2; ++m) {
#pragma unroll
        for (int j = 0; j < 4; ++j) {
          int row = mt * 128 + wm + m * 16 + (l >> 4) * 4 + j;
          out[(size_t)row * 32000 + col] = acc[m][n][j] + bv;
        }
      }
    }
    __syncthreads();                   // all reads done before next tile stages
  }
}

// ---------------- launch ----------------
extern "C" void kernel_launch(void* const* d_in, const int* in_sizes, int n_in,
                              void* d_out, int out_size, void* d_ws, size_t ws_size,
                              hipStream_t stream) {
  const float* x    = (const float*)d_in[0];
  const float* W_ih = (const float*)d_in[1];
  const float* W_hh = (const float*)d_in[2];
  const float* b_ih = (const float*)d_in[3];
  const float* b_hh = (const float*)d_in[4];
  const float* W_fc = (const float*)d_in[5];
  const float* b_fc = (const float*)d_in[6];
  float* out = (float*)d_out;                  // [2048][32000] f32

  char* ws = (char*)d_ws;
  unsigned long long* pairs = (unsigned long long*)ws;       // 2*512*8 = 8,192
  unsigned* sumR  = (unsigned*)(ws + 8192);                  // 16*32*4 = 2,048
  unsigned* sumG  = (unsigned*)(ws + 10240);                 // 16*16*4 = 1,024
  f16*   hs16  = (f16*)(ws + 16384);                         // 4,196,352
  float* xp    = (float*)(ws + 4212736);                     // 8,388,608
  f16*   x16   = (f16*)(ws + 12601344);                      // 4,194,304
  f16*   wih16 = (f16*)(ws + 16795648);                      // 2,097,152
  f16*   wfc16 = (f16*)(ws + 18892800);                      // 65,536,000
  float* bsum  = (float*)(ws + 84428800);                    // 4,096 (total ~84.4MB)

  k_clear<<<4, 256, 0, stream>>>(pairs, 2 * 512, sumR, 16 * 32, sumG, 16 * 16);
  k_cvt<<<1024, 256, 0, stream>>>(x, x16, 2048 * 1024 / 4);
  k_cvt<<<1024, 256, 0, stream>>>(W_ih, wih16, 1024 * 1024 / 4);
  k_cvt<<<2048, 256, 0, stream>>>(W_fc, wfc16, 32000 * 1024 / 4);
  k_bias<<<4, 256, 0, stream>>>(b_ih, b_hh, bsum);

  // xp = x @ W_ih^T + (b_ih + b_hh)
  k_gemm<<<dim3(8, 16), 256, 0, stream>>>(x16, wih16, bsum, xp, 1024);

  // fused: recurrence + head GEMM overlap
  k_main<<<NBLK + NGWK, 1024, 0, stream>>>(W_hh, xp, pairs, sumR, sumG, hs16,
                                           wfc16, b_fc, out);
}